// Round 4
// baseline (10770.039 us; speedup 1.0000x reference)
//
#include <hip/hip_runtime.h>
#include <stdint.h>

#define NBATCH 16
#define NPTS   131072
#define NPOINT 4096
#define KWG    16                  // workgroups per batch
#define TPB    1024
#define PPT    (NPTS / KWG / TPB)  // 8 points per thread

typedef unsigned long long u64;
typedef unsigned int u32;

__device__ __forceinline__ u64 shfl_xor_u64(u64 v, int m) {
    u32 lo = (u32)v, hi = (u32)(v >> 32);
    lo = (u32)__shfl_xor((int)lo, m, 64);
    hi = (u32)__shfl_xor((int)hi, m, 64);
    return ((u64)hi << 32) | (u64)lo;
}

// key layout: [tag:15][dist_bits:32][inv_idx:17]
// dist >= 0 so fp32 bit pattern is order-preserving; inv_idx = NPTS-1-idx
// makes "max key" == (max dist, then min idx) == np.argmax first-occurrence.

__global__ __launch_bounds__(TPB, 4) void fps_kernel(
    const float* __restrict__ xyz,   // [B][N][3]
    const int*   __restrict__ finit, // [B]
    int*         __restrict__ out,   // [B][NPOINT]
    u64*         __restrict__ slots) // [B][KWG][2]
{
    const int b   = blockIdx.x >> 4;
    const int w   = blockIdx.x & 15;
    const int tid = threadIdx.x;

    const float* xb = xyz + (size_t)b * NPTS * 3;
    const int base = w * (NPTS / KWG);

    // per-thread point state, all in registers
    float px[PPT], py[PPT], pz[PPT], pd[PPT];
    u32 inv[PPT];
    #pragma unroll
    for (int j = 0; j < PPT; ++j) {
        int idx = base + j * TPB + tid;          // strided: coalesced initial load
        px[j] = xb[(size_t)idx * 3 + 0];
        py[j] = xb[(size_t)idx * 3 + 1];
        pz[j] = xb[(size_t)idx * 3 + 2];
        pd[j] = 1e10f;                            // INF from reference (exact in fp32)
        inv[j] = (u32)(NPTS - 1 - idx);
    }

    __shared__ u64 lds_keys[TPB / 64];
    __shared__ int lds_best;

    const int f0 = finit[b];
    if (w == 0 && tid == 0) out[b * NPOINT] = f0;  // y_0 = farthest_init
    float cx = xb[(size_t)f0 * 3 + 0];
    float cy = xb[(size_t)f0 * 3 + 1];
    float cz = xb[(size_t)f0 * 3 + 2];

    u64* bslots = slots + (size_t)b * KWG * 2;

    for (int t = 1; t < NPOINT; ++t) {
        // ---- distance update + thread-local argmax (registers only) ----
        // Match XLA's fused square+reduce contraction:
        //   acc = fma(dz,dz, fma(dy,dy, dx*dx)), each op correctly rounded.
        u64 bestkey = 0;
        #pragma unroll
        for (int j = 0; j < PPT; ++j) {
            float dx = __fsub_rn(px[j], cx);
            float dy = __fsub_rn(py[j], cy);
            float dz = __fsub_rn(pz[j], cz);
            float d  = __fmaf_rn(dz, dz, __fmaf_rn(dy, dy, __fmul_rn(dx, dx)));
            float nd = fminf(pd[j], d);
            pd[j] = nd;
            u64 key = ((u64)__float_as_uint(nd) << 17) | (u64)inv[j];
            bestkey = key > bestkey ? key : bestkey;
        }
        // ---- wave reduce (64 lanes) ----
        #pragma unroll
        for (int s = 1; s < 64; s <<= 1) {
            u64 o = shfl_xor_u64(bestkey, s);
            bestkey = o > bestkey ? o : bestkey;
        }
        if ((tid & 63) == 0) lds_keys[tid >> 6] = bestkey;
        __syncthreads();

        const int p = t & 1;
        if (tid < 64) {  // wave 0 does block reduce + publish + poll + final reduce
            u64 blk = (tid < (TPB / 64)) ? lds_keys[tid] : 0;
            #pragma unroll
            for (int s = 1; s < 16; s <<= 1) {
                u64 o = shfl_xor_u64(blk, s);
                blk = o > blk ? o : blk;
            }
            if (tid == 0) {
                u64 tagged = ((u64)(u32)t << 49) | blk;
                __hip_atomic_store(&bslots[(w << 1) | p], tagged,
                                   __ATOMIC_RELAXED, __HIP_MEMORY_SCOPE_AGENT);
            }
            u64 got = 0;
            if (tid < KWG) {  // lane l polls batch-peer l's slot for this round's tag
                u64* sp = &bslots[(tid << 1) | p];
                do {
                    got = __hip_atomic_load(sp, __ATOMIC_RELAXED,
                                            __HIP_MEMORY_SCOPE_AGENT);
                } while ((got >> 49) != (u64)(u32)t);
            }
            #pragma unroll
            for (int s = 1; s < 16; s <<= 1) {
                u64 o = shfl_xor_u64(got, s);
                got = o > got ? o : got;
            }
            if (tid == 0) {
                int bi = (NPTS - 1) - (int)(got & 0x1FFFF);
                if (w == 0) out[b * NPOINT + t] = bi;
                lds_best = bi;
            }
        }
        __syncthreads();
        const int bi = lds_best;
        cx = xb[(size_t)bi * 3 + 0];
        cy = xb[(size_t)bi * 3 + 1];
        cz = xb[(size_t)bi * 3 + 2];
    }
}

extern "C" void kernel_launch(void* const* d_in, const int* in_sizes, int n_in,
                              void* d_out, int out_size, void* d_ws, size_t ws_size,
                              hipStream_t stream) {
    const float* xyz   = (const float*)d_in[0];
    const int*   finit = (const int*)d_in[1];
    int*         out   = (int*)d_out;
    u64*         slots = (u64*)d_ws;   // B*KWG*2*8 = 4 KiB; tag-checked, no init

    void* args[] = { (void*)&xyz, (void*)&finit, (void*)&out, (void*)&slots };
    dim3 grid(NBATCH * KWG), block(TPB);
    hipError_t err = hipLaunchCooperativeKernel((const void*)fps_kernel, grid, block,
                                                args, 0, stream);
    if (err != hipSuccess) {
        // co-residency still holds: 256 blocks x 16 waves, 1 block/CU
        fps_kernel<<<grid, block, 0, stream>>>(xyz, finit, out, slots);
    }
}